// Round 3
// baseline (1316.272 us; speedup 1.0000x reference)
//
#include <hip/hip_runtime.h>
#include <math.h>

#define FDIM 64
#define RDIM 16
#define LN2F 0.69314718055994530942f

// Numerically stable softplus
__device__ __forceinline__ float sp(float x) {
    return fmaxf(x, 0.0f) + log1pf(__expf(-fabsf(x)));
}

// ---------------- per-atom kernels (barrier-free waves, 4 atoms in flight) --

// fused: histogram of idx_i  +  x = sp(emb)-ln2; v = sp(x@Wi+bi); y = sp(x@Wj+bj)
__global__ __launch_bounds__(256) void k_atoms(
    const float* __restrict__ emb,
    const float* __restrict__ Wi, const float* __restrict__ bi,
    const float* __restrict__ Wj, const float* __restrict__ bj,
    const int* __restrict__ idx_i, int* __restrict__ cnt,
    float* __restrict__ v, float* __restrict__ y, int N, int P)
{
    // phase A: histogram (independent of phase B; waves interleave freely)
    {
        int t = blockIdx.x * blockDim.x + threadIdx.x;
        int n = gridDim.x * blockDim.x;
        for (int p = t; p < P; p += n) atomicAdd(&cnt[idx_i[p]], 1);
    }
    // phase B: per-atom matvecs, wave-private LDS (no __syncthreads)
    const int c = threadIdx.x & 63;
    const int w = threadIdx.x >> 6;
    float wi[FDIM], wj[FDIM];
#pragma unroll
    for (int k = 0; k < FDIM; ++k) {
        wi[k] = Wi[k * FDIM + c];
        wj[k] = Wj[k * FDIM + c];
    }
    const float bic = bi[c], bjc = bj[c];
    __shared__ __align__(16) float xb[4][4][FDIM];
    const int wv = blockIdx.x * 4 + w;
    const int nw = gridDim.x * 4;
    for (int base = wv * 4; base < N; base += nw * 4) {
#pragma unroll
        for (int m = 0; m < 4; ++m) {
            int a = base + m;
            float e = (a < N) ? emb[(size_t)a * FDIM + c] : 0.0f;
            xb[w][m][c] = sp(e) - LN2F;
        }
        float ai[4], aj[4];
#pragma unroll
        for (int m = 0; m < 4; ++m) { ai[m] = bic; aj[m] = bjc; }
#pragma unroll
        for (int k4 = 0; k4 < FDIM / 4; ++k4) {
#pragma unroll
            for (int m = 0; m < 4; ++m) {
                float4 x4 = ((const float4*)xb[w][m])[k4];
                ai[m] = fmaf(x4.x, wi[4*k4+0], ai[m]); aj[m] = fmaf(x4.x, wj[4*k4+0], aj[m]);
                ai[m] = fmaf(x4.y, wi[4*k4+1], ai[m]); aj[m] = fmaf(x4.y, wj[4*k4+1], aj[m]);
                ai[m] = fmaf(x4.z, wi[4*k4+2], ai[m]); aj[m] = fmaf(x4.z, wj[4*k4+2], aj[m]);
                ai[m] = fmaf(x4.w, wi[4*k4+3], ai[m]); aj[m] = fmaf(x4.w, wj[4*k4+3], aj[m]);
            }
        }
#pragma unroll
        for (int m = 0; m < 4; ++m) {
            int a = base + m;
            if (a < N) {
                v[(size_t)a * FDIM + c] = sp(ai[m]);
                y[(size_t)a * FDIM + c] = sp(aj[m]);
            }
        }
    }
}

// one residual block: v += sp(v@W1+b1)@W2 + b2
__global__ __launch_bounds__(256) void k_res(
    const float* __restrict__ W1, const float* __restrict__ b1,
    const float* __restrict__ W2, const float* __restrict__ b2,
    float* __restrict__ v, int N)
{
    const int c = threadIdx.x & 63;
    const int w = threadIdx.x >> 6;
    float w1[FDIM], w2[FDIM];
#pragma unroll
    for (int k = 0; k < FDIM; ++k) {
        w1[k] = W1[k * FDIM + c];
        w2[k] = W2[k * FDIM + c];
    }
    const float b1c = b1[c], b2c = b2[c];
    __shared__ __align__(16) float xb[4][4][FDIM];
    __shared__ __align__(16) float hb[4][4][FDIM];
    const int wv = blockIdx.x * 4 + w;
    const int nw = gridDim.x * 4;
    for (int base = wv * 4; base < N; base += nw * 4) {
        float vv[4];
#pragma unroll
        for (int m = 0; m < 4; ++m) {
            int a = base + m;
            vv[m] = (a < N) ? v[(size_t)a * FDIM + c] : 0.0f;
            xb[w][m][c] = vv[m];
        }
        float a1[4];
#pragma unroll
        for (int m = 0; m < 4; ++m) a1[m] = b1c;
#pragma unroll
        for (int k4 = 0; k4 < FDIM / 4; ++k4) {
#pragma unroll
            for (int m = 0; m < 4; ++m) {
                float4 x4 = ((const float4*)xb[w][m])[k4];
                a1[m] = fmaf(x4.x, w1[4*k4+0], a1[m]);
                a1[m] = fmaf(x4.y, w1[4*k4+1], a1[m]);
                a1[m] = fmaf(x4.z, w1[4*k4+2], a1[m]);
                a1[m] = fmaf(x4.w, w1[4*k4+3], a1[m]);
            }
        }
#pragma unroll
        for (int m = 0; m < 4; ++m) hb[w][m][c] = sp(a1[m]);
        float a2[4];
#pragma unroll
        for (int m = 0; m < 4; ++m) a2[m] = b2c;
#pragma unroll
        for (int k4 = 0; k4 < FDIM / 4; ++k4) {
#pragma unroll
            for (int m = 0; m < 4; ++m) {
                float4 h4 = ((const float4*)hb[w][m])[k4];
                a2[m] = fmaf(h4.x, w2[4*k4+0], a2[m]);
                a2[m] = fmaf(h4.y, w2[4*k4+1], a2[m]);
                a2[m] = fmaf(h4.z, w2[4*k4+2], a2[m]);
                a2[m] = fmaf(h4.w, w2[4*k4+3], a2[m]);
            }
        }
#pragma unroll
        for (int m = 0; m < 4; ++m) {
            int a = base + m;
            if (a < N) v[(size_t)a * FDIM + c] = vv[m] + a2[m];
        }
    }
}

// out = sp(v) @ Wv + bv  (in-place: v IS d_out)
__global__ __launch_bounds__(256) void k_final(
    const float* __restrict__ Wv, const float* __restrict__ bv,
    float* __restrict__ v, int N)
{
    const int c = threadIdx.x & 63;
    const int w = threadIdx.x >> 6;
    float wv[FDIM];
#pragma unroll
    for (int k = 0; k < FDIM; ++k) wv[k] = Wv[k * FDIM + c];
    const float bvc = bv[c];
    __shared__ __align__(16) float xb[4][4][FDIM];
    const int wvid = blockIdx.x * 4 + w;
    const int nw = gridDim.x * 4;
    for (int base = wvid * 4; base < N; base += nw * 4) {
#pragma unroll
        for (int m = 0; m < 4; ++m) {
            int a = base + m;
            float t = (a < N) ? v[(size_t)a * FDIM + c] : 0.0f;
            xb[w][m][c] = sp(t);
        }
        float ac[4];
#pragma unroll
        for (int m = 0; m < 4; ++m) ac[m] = bvc;
#pragma unroll
        for (int k4 = 0; k4 < FDIM / 4; ++k4) {
#pragma unroll
            for (int m = 0; m < 4; ++m) {
                float4 x4 = ((const float4*)xb[w][m])[k4];
                ac[m] = fmaf(x4.x, wv[4*k4+0], ac[m]);
                ac[m] = fmaf(x4.y, wv[4*k4+1], ac[m]);
                ac[m] = fmaf(x4.z, wv[4*k4+2], ac[m]);
                ac[m] = fmaf(x4.w, wv[4*k4+3], ac[m]);
            }
        }
#pragma unroll
        for (int m = 0; m < 4; ++m) {
            int a = base + m;
            if (a < N) v[(size_t)a * FDIM + c] = ac[m];
        }
    }
}

// ---------------- pair path: counting sort + segment sum ----------------

__global__ __launch_bounds__(256) void k_scan_a(
    const int* __restrict__ cnt, int* __restrict__ part, int N)
{
    __shared__ int red[256];
    int b = blockIdx.x, t = threadIdx.x;
    int base = b * 1024 + t * 4;
    int s = 0;
#pragma unroll
    for (int i = 0; i < 4; ++i) { int a = base + i; if (a < N) s += cnt[a]; }
    red[t] = s; __syncthreads();
    for (int off = 128; off > 0; off >>= 1) {
        if (t < off) red[t] += red[t + off];
        __syncthreads();
    }
    if (t == 0) part[b] = red[0];
}

__global__ __launch_bounds__(256) void k_scan_b(int* __restrict__ part, int nPart)
{
    __shared__ int lds[256];
    int t = threadIdx.x;
    int base = t * 4;
    int v[4]; int s = 0;
#pragma unroll
    for (int i = 0; i < 4; ++i) { v[i] = (base + i < nPart) ? part[base + i] : 0; s += v[i]; }
    lds[t] = s; __syncthreads();
    int run = s;
    for (int off = 1; off < 256; off <<= 1) {
        int x = (t >= off) ? lds[t - off] : 0;
        __syncthreads();
        lds[t] += x;
        __syncthreads();
    }
    int excl = lds[t] - run;
#pragma unroll
    for (int i = 0; i < 4; ++i) { if (base + i < nPart) { part[base + i] = excl; excl += v[i]; } }
}

__global__ __launch_bounds__(256) void k_scan_c(
    const int* __restrict__ cnt, const int* __restrict__ part,
    int* __restrict__ start, int* __restrict__ cursor, int N, int P)
{
    __shared__ int lds[256];
    int b = blockIdx.x, t = threadIdx.x;
    int base = b * 1024 + t * 4;
    int v[4]; int s = 0;
#pragma unroll
    for (int i = 0; i < 4; ++i) { int a = base + i; v[i] = (a < N) ? cnt[a] : 0; s += v[i]; }
    lds[t] = s; __syncthreads();
    int run = s;
    for (int off = 1; off < 256; off <<= 1) {
        int x = (t >= off) ? lds[t - off] : 0;
        __syncthreads();
        lds[t] += x;
        __syncthreads();
    }
    int pre = part[b] + (lds[t] - run);
#pragma unroll
    for (int i = 0; i < 4; ++i) {
        int a = base + i;
        if (a < N) { start[a] = pre; cursor[a] = pre; pre += v[i]; }
    }
    if (b == 0 && t == 0) start[N] = P;
}

__global__ __launch_bounds__(256) void k_scatter(
    const int* __restrict__ pidx, int* __restrict__ cursor,
    int2* __restrict__ sorted, int P)
{
    int t = blockIdx.x * blockDim.x + threadIdx.x;
    int n = gridDim.x * blockDim.x;
    for (int p = t; p < P; p += n) {
        int i = pidx[p], j = pidx[P + p];
        int pos = atomicAdd(&cursor[i], 1);
        sorted[pos] = make_int2(p, j);
    }
}

__device__ __forceinline__ float dot16(const float4* f,
                                       float4 g0, float4 g1, float4 g2, float4 g3)
{
    float4 a0 = f[0], a1 = f[1], a2 = f[2], a3 = f[3];
    float d = a0.x * g0.x;
    d = fmaf(a0.y, g0.y, d); d = fmaf(a0.z, g0.z, d); d = fmaf(a0.w, g0.w, d);
    d = fmaf(a1.x, g1.x, d); d = fmaf(a1.y, g1.y, d); d = fmaf(a1.z, g1.z, d); d = fmaf(a1.w, g1.w, d);
    d = fmaf(a2.x, g2.x, d); d = fmaf(a2.y, g2.y, d); d = fmaf(a2.z, g2.z, d); d = fmaf(a2.w, g2.w, d);
    d = fmaf(a3.x, g3.x, d); d = fmaf(a3.y, g3.y, d); d = fmaf(a3.z, g3.z, d); d = fmaf(a3.w, g3.w, d);
    return d;
}

// one wave per atom; 4 pairs in flight
__global__ __launch_bounds__(256) void k_seg(
    const int2* __restrict__ sorted, const int* __restrict__ start,
    const float* __restrict__ f_ij, const float* __restrict__ G,
    const float* __restrict__ y, float* __restrict__ v, int N)
{
    const int c = threadIdx.x & 63;
    const int w = (blockIdx.x << 2) | (threadIdx.x >> 6);
    const int nw = gridDim.x << 2;
    float4 g0, g1, g2, g3;
    {
        const float4* gp = (const float4*)(G + c * RDIM);
        g0 = gp[0]; g1 = gp[1]; g2 = gp[2]; g3 = gp[3];
    }
    for (int a = w; a < N; a += nw) {
        const int s = start[a], e = start[a + 1];
        float acc = 0.0f;
        int q = s;
        for (; q + 4 <= e; q += 4) {
            int2 E[4];
#pragma unroll
            for (int t = 0; t < 4; ++t) E[t] = sorted[q + t];
            float4 F[4][4];
            float yv[4];
#pragma unroll
            for (int t = 0; t < 4; ++t) {
                const float4* fp = (const float4*)(f_ij + (size_t)E[t].x * RDIM);
                F[t][0] = fp[0]; F[t][1] = fp[1]; F[t][2] = fp[2]; F[t][3] = fp[3];
                yv[t] = y[(size_t)E[t].y * FDIM + c];
            }
#pragma unroll
            for (int t = 0; t < 4; ++t) {
                float d = dot16(F[t], g0, g1, g2, g3);
                acc = fmaf(d, yv[t], acc);
            }
        }
        for (; q < e; ++q) {
            int2 e0 = sorted[q];
            const float4* fp = (const float4*)(f_ij + (size_t)e0.x * RDIM);
            float4 F0[4];
            F0[0] = fp[0]; F0[1] = fp[1]; F0[2] = fp[2]; F0[3] = fp[3];
            float yv = y[(size_t)e0.y * FDIM + c];
            acc = fmaf(dot16(F0, g0, g1, g2, g3), yv, acc);
        }
        v[(size_t)a * FDIM + c] += acc;
    }
}

extern "C" void kernel_launch(void* const* d_in, const int* in_sizes, int n_in,
                              void* d_out, int out_size, void* d_ws, size_t ws_size,
                              hipStream_t stream)
{
    const int*   pidx = (const int*)d_in[0];    // [2, P]
    const float* f_ij = (const float*)d_in[1];  // [P, 1, R]
    const float* emb  = (const float*)d_in[3];  // [N, F]
    const float* G    = (const float*)d_in[4];  // [F, R]
    const float* Wi   = (const float*)d_in[5];
    const float* bi   = (const float*)d_in[6];
    const float* Wj   = (const float*)d_in[7];
    const float* bj   = (const float*)d_in[8];
    const float* rW1  = (const float*)d_in[9];
    const float* rb1  = (const float*)d_in[10];
    const float* rW2  = (const float*)d_in[11];
    const float* rb2  = (const float*)d_in[12];
    const float* Wv   = (const float*)d_in[13];
    const float* bv   = (const float*)d_in[14];

    const int P = in_sizes[0] / 2;
    const int N = in_sizes[3] / FDIM;

    float* v = (float*)d_out;

    // workspace layout
    char* ws = (char*)d_ws;
    size_t off = 0;
    float* y      = (float*)(ws + off); off += (size_t)N * FDIM * 4;
    int*   cnt    = (int*)(ws + off);   off += (size_t)N * 4;
    int*   start  = (int*)(ws + off);   off += (size_t)(N + 1) * 4;
    int*   cursor = (int*)(ws + off);   off += (size_t)N * 4;
    off = (off + 15) & ~(size_t)15;
    int*   part   = (int*)(ws + off);   off += (size_t)4096 * 4;
    off = (off + 15) & ~(size_t)15;
    int2*  sorted = (int2*)(ws + off);  off += (size_t)P * 8;

    const int nPart = (N + 1023) / 1024;

    dim3 blk(256);
    hipMemsetAsync(cnt, 0, (size_t)N * 4, stream);
    k_atoms<<<1024, blk, 0, stream>>>(emb, Wi, bi, Wj, bj, pidx, cnt, v, y, N, P);
    k_scan_a<<<nPart, blk, 0, stream>>>(cnt, part, N);
    k_scan_b<<<1, blk, 0, stream>>>(part, nPart);
    k_scan_c<<<nPart, blk, 0, stream>>>(cnt, part, start, cursor, N, P);
    k_scatter<<<2048, blk, 0, stream>>>(pidx, cursor, sorted, P);
    k_seg<<<4096, blk, 0, stream>>>(sorted, start, f_ij, G, y, v, N);
    for (int l = 0; l < 3; ++l) {
        k_res<<<1024, blk, 0, stream>>>(rW1 + l * FDIM * FDIM, rb1 + l * FDIM,
                                        rW2 + l * FDIM * FDIM, rb2 + l * FDIM, v, N);
    }
    k_final<<<1024, blk, 0, stream>>>(Wv, bv, v, N);
}

// Round 4
// 1133.534 us; speedup vs baseline: 1.1612x; 1.1612x over previous
//
#include <hip/hip_runtime.h>
#include <math.h>

#define FDIM 64
#define RDIM 16
#define LN2F 0.69314718055994530942f
#define TP 68   // padded LDS tile row stride (floats); 68*4 B keeps 16-B align

// Numerically stable softplus (fast intrinsics)
__device__ __forceinline__ float sp(float x) {
    return fmaxf(x, 0.0f) + __logf(1.0f + __expf(-fabsf(x)));
}

// ---------------- weight transpose: dst[c*64+k] = src[k*64+c] ----------------
__global__ __launch_bounds__(256) void k_tr(
    const float* s0, const float* s1, const float* s2, const float* s3,
    const float* s4, const float* s5, const float* s6, const float* s7,
    const float* s8, float* __restrict__ dst)
{
    const float* srcs[9] = {s0, s1, s2, s3, s4, s5, s6, s7, s8};
    const float* s = srcs[blockIdx.x];
    float* d = dst + (size_t)blockIdx.x * 4096;
    for (int i = threadIdx.x; i < 4096; i += 256)
        d[(i & 63) * 64 + (i >> 6)] = s[i];
}

// ---------------- histogram ----------------
__global__ __launch_bounds__(256) void k_hist(
    const int* __restrict__ idx_i, int* __restrict__ cnt, int P)
{
    int t = blockIdx.x * blockDim.x + threadIdx.x;
    int n = gridDim.x * blockDim.x;
    for (int p = t; p < P; p += n) atomicAdd(&cnt[idx_i[p]], 1);
}

// ---------------- tile helpers (lane = atom, weights via SGPR) ----------------

// coalesced copy global[a0..a0+63][0..63] -> padded LDS tile (zero-fill OOB rows)
__device__ __forceinline__ void tile_in(float* T, const float* __restrict__ src,
                                        int a0, int rows, int lane)
{
#pragma unroll 4
    for (int i = 0; i < 16; ++i) {
        int r = i * 4 + (lane >> 4);
        int col = (lane & 15) * 4;
        float4 val = make_float4(0.f, 0.f, 0.f, 0.f);
        if (r < rows) val = *(const float4*)&src[(size_t)(a0 + r) * FDIM + col];
        *(float4*)&T[r * TP + col] = val;
    }
}

__device__ __forceinline__ void tile_out(float* __restrict__ dst, const float* T,
                                         int a0, int rows, int lane)
{
#pragma unroll 4
    for (int i = 0; i < 16; ++i) {
        int r = i * 4 + (lane >> 4);
        int col = (lane & 15) * 4;
        if (r < rows)
            *(float4*)&dst[(size_t)(a0 + r) * FDIM + col] = *(const float4*)&T[r * TP + col];
    }
}

// read this lane's atom row from tile into registers
__device__ __forceinline__ void row_read(const float* T, int lane, float (&x)[FDIM])
{
#pragma unroll
    for (int k4 = 0; k4 < 16; ++k4) {
        float4 t4 = *(const float4*)&T[lane * TP + k4 * 4];
        x[4 * k4 + 0] = t4.x; x[4 * k4 + 1] = t4.y;
        x[4 * k4 + 2] = t4.z; x[4 * k4 + 3] = t4.w;
    }
}

// one matvec: for each output c, acc = b[c] + sum_k x[k]*WT[c][k]; write (sp?) to tile.
// WT rows are contiguous (pre-transposed) and addresses wave-uniform -> s_load;
// x[k] are per-lane VGPRs -> v_fma with one SGPR operand.
__device__ __forceinline__ void mv_write(float* T, const float (&x)[FDIM],
                                         const float* __restrict__ wt,
                                         const float* __restrict__ b,
                                         int lane, bool act)
{
    for (int c2 = 0; c2 < 32; ++c2) {
        float2 o;
#pragma unroll
        for (int u = 0; u < 2; ++u) {
            int c = c2 * 2 + u;
            const float* wc = wt + c * FDIM;
            float acc = b[c];
#pragma unroll
            for (int k = 0; k < FDIM; ++k) acc = fmaf(x[k], wc[k], acc);
            (&o.x)[u] = act ? sp(acc) : acc;
        }
        *(float2*)&T[lane * TP + c2 * 2] = o;
    }
}

// ---------------- k_atoms: x=sp(emb)-ln2; v=sp(x@Wi+bi); y=sp(x@Wj+bj) --------
__global__ __launch_bounds__(256) void k_atoms(
    const float* __restrict__ emb,
    const float* __restrict__ wti, const float* __restrict__ bi,
    const float* __restrict__ wtj, const float* __restrict__ bj,
    float* __restrict__ v, float* __restrict__ y, int N)
{
    __shared__ float tile[4][64 * TP];
    const int lane = threadIdx.x & 63;
    const int wv = threadIdx.x >> 6;
    float* T = tile[wv];
    const int nTiles = (N + 63) >> 6;
    const int nW = gridDim.x * 4;
    for (int t = blockIdx.x * 4 + wv; t < nTiles; t += nW) {
        const int a0 = t << 6;
        const int rows = min(64, N - a0);
        tile_in(T, emb, a0, rows, lane);
        float x[FDIM];
        row_read(T, lane, x);
#pragma unroll
        for (int k = 0; k < FDIM; ++k) x[k] = sp(x[k]) - LN2F;
        mv_write(T, x, wti, bi, lane, true);
        tile_out(v, T, a0, rows, lane);
        mv_write(T, x, wtj, bj, lane, true);
        tile_out(y, T, a0, rows, lane);
    }
}

// ---------------- k_post: fused 3 residual blocks + final projection ---------
__global__ __launch_bounds__(256) void k_post(
    const float* __restrict__ wt_res,  // per l: [W1^T | W2^T], each 4096 floats
    const float* __restrict__ rb1, const float* __restrict__ rb2,
    const float* __restrict__ wtv, const float* __restrict__ bv,
    float* __restrict__ v, int N)
{
    __shared__ float tile[4][64 * TP];
    const int lane = threadIdx.x & 63;
    const int wv = threadIdx.x >> 6;
    float* T = tile[wv];
    const int nTiles = (N + 63) >> 6;
    const int nW = gridDim.x * 4;
    for (int t = blockIdx.x * 4 + wv; t < nTiles; t += nW) {
        const int a0 = t << 6;
        const int rows = min(64, N - a0);
        tile_in(T, v, a0, rows, lane);
        float xv[FDIM];
        row_read(T, lane, xv);
        for (int l = 0; l < 3; ++l) {
            const float* wt1 = wt_res + (size_t)l * 8192;
            const float* wt2 = wt1 + 4096;
            mv_write(T, xv, wt1, rb1 + l * FDIM, lane, true);   // h = sp(v@W1+b1)
            float h[FDIM];
            row_read(T, lane, h);
            mv_write(T, h, wt2, rb2 + l * FDIM, lane, false);   // d = h@W2+b2
            float d[FDIM];
            row_read(T, lane, d);
#pragma unroll
            for (int k = 0; k < FDIM; ++k) xv[k] += d[k];       // v += d
        }
        float hf[FDIM];
#pragma unroll
        for (int k = 0; k < FDIM; ++k) hf[k] = sp(xv[k]);
        mv_write(T, hf, wtv, bv, lane, false);                  // out = sp(v)@Wv+bv
        tile_out(v, T, a0, rows, lane);
    }
}

// ---------------- scan / scatter (unchanged) ----------------
__global__ __launch_bounds__(256) void k_scan_a(
    const int* __restrict__ cnt, int* __restrict__ part, int N)
{
    __shared__ int red[256];
    int b = blockIdx.x, t = threadIdx.x;
    int base = b * 1024 + t * 4;
    int s = 0;
#pragma unroll
    for (int i = 0; i < 4; ++i) { int a = base + i; if (a < N) s += cnt[a]; }
    red[t] = s; __syncthreads();
    for (int off = 128; off > 0; off >>= 1) {
        if (t < off) red[t] += red[t + off];
        __syncthreads();
    }
    if (t == 0) part[b] = red[0];
}

__global__ __launch_bounds__(256) void k_scan_b(int* __restrict__ part, int nPart)
{
    __shared__ int lds[256];
    int t = threadIdx.x;
    int base = t * 4;
    int v[4]; int s = 0;
#pragma unroll
    for (int i = 0; i < 4; ++i) { v[i] = (base + i < nPart) ? part[base + i] : 0; s += v[i]; }
    lds[t] = s; __syncthreads();
    int run = s;
    for (int off = 1; off < 256; off <<= 1) {
        int x = (t >= off) ? lds[t - off] : 0;
        __syncthreads();
        lds[t] += x;
        __syncthreads();
    }
    int excl = lds[t] - run;
#pragma unroll
    for (int i = 0; i < 4; ++i) { if (base + i < nPart) { part[base + i] = excl; excl += v[i]; } }
}

__global__ __launch_bounds__(256) void k_scan_c(
    const int* __restrict__ cnt, const int* __restrict__ part,
    int* __restrict__ start, int* __restrict__ cursor, int N, int P)
{
    __shared__ int lds[256];
    int b = blockIdx.x, t = threadIdx.x;
    int base = b * 1024 + t * 4;
    int v[4]; int s = 0;
#pragma unroll
    for (int i = 0; i < 4; ++i) { int a = base + i; v[i] = (a < N) ? cnt[a] : 0; s += v[i]; }
    lds[t] = s; __syncthreads();
    int run = s;
    for (int off = 1; off < 256; off <<= 1) {
        int x = (t >= off) ? lds[t - off] : 0;
        __syncthreads();
        lds[t] += x;
        __syncthreads();
    }
    int pre = part[b] + (lds[t] - run);
#pragma unroll
    for (int i = 0; i < 4; ++i) {
        int a = base + i;
        if (a < N) { start[a] = pre; cursor[a] = pre; pre += v[i]; }
    }
    if (b == 0 && t == 0) start[N] = P;
}

__global__ __launch_bounds__(256) void k_scatter(
    const int* __restrict__ pidx, int* __restrict__ cursor,
    int2* __restrict__ sorted, int P)
{
    int t = blockIdx.x * blockDim.x + threadIdx.x;
    int n = gridDim.x * blockDim.x;
    for (int p = t; p < P; p += n) {
        int i = pidx[p], j = pidx[P + p];
        int pos = atomicAdd(&cursor[i], 1);
        sorted[pos] = make_int2(p, j);
    }
}

// ---------------- k_seg: scalar-path f/sorted, VMEM only for y gather --------
__device__ __forceinline__ float fdot(const float* __restrict__ f,
                                      float4 g0, float4 g1, float4 g2, float4 g3)
{
    // f[] address is wave-uniform -> s_load; g* per-lane VGPR
    float d = f[0] * g0.x;
    d = fmaf(f[1], g0.y, d);  d = fmaf(f[2], g0.z, d);  d = fmaf(f[3], g0.w, d);
    d = fmaf(f[4], g1.x, d);  d = fmaf(f[5], g1.y, d);  d = fmaf(f[6], g1.z, d);  d = fmaf(f[7], g1.w, d);
    d = fmaf(f[8], g2.x, d);  d = fmaf(f[9], g2.y, d);  d = fmaf(f[10], g2.z, d); d = fmaf(f[11], g2.w, d);
    d = fmaf(f[12], g3.x, d); d = fmaf(f[13], g3.y, d); d = fmaf(f[14], g3.z, d); d = fmaf(f[15], g3.w, d);
    return d;
}

__global__ __launch_bounds__(256) void k_seg(
    const int2* __restrict__ sorted, const int* __restrict__ start,
    const float* __restrict__ f_ij, const float* __restrict__ G,
    const float* __restrict__ y, float* __restrict__ v, int N)
{
    const int c = threadIdx.x & 63;
    int w0 = (blockIdx.x << 2) | (threadIdx.x >> 6);
    const int w = __builtin_amdgcn_readfirstlane(w0);   // provably uniform
    const int nw = gridDim.x << 2;
    float4 g0, g1, g2, g3;
    {
        const float4* gp = (const float4*)(G + c * RDIM);
        g0 = gp[0]; g1 = gp[1]; g2 = gp[2]; g3 = gp[3];
    }
    for (int a = w; a < N; a += nw) {
        const int s = start[a], e = start[a + 1];
        float acc = 0.0f;
        int q = s;
        for (; q + 4 <= e; q += 4) {
            int2 E0 = sorted[q + 0], E1 = sorted[q + 1];
            int2 E2 = sorted[q + 2], E3 = sorted[q + 3];
            float yv0 = y[(size_t)E0.y * FDIM + c];
            float yv1 = y[(size_t)E1.y * FDIM + c];
            float yv2 = y[(size_t)E2.y * FDIM + c];
            float yv3 = y[(size_t)E3.y * FDIM + c];
            float d0 = fdot(f_ij + (size_t)E0.x * RDIM, g0, g1, g2, g3);
            float d1 = fdot(f_ij + (size_t)E1.x * RDIM, g0, g1, g2, g3);
            float d2 = fdot(f_ij + (size_t)E2.x * RDIM, g0, g1, g2, g3);
            float d3 = fdot(f_ij + (size_t)E3.x * RDIM, g0, g1, g2, g3);
            acc = fmaf(d0, yv0, acc);
            acc = fmaf(d1, yv1, acc);
            acc = fmaf(d2, yv2, acc);
            acc = fmaf(d3, yv3, acc);
        }
        for (; q < e; ++q) {
            int2 E0 = sorted[q];
            float yv0 = y[(size_t)E0.y * FDIM + c];
            float d0 = fdot(f_ij + (size_t)E0.x * RDIM, g0, g1, g2, g3);
            acc = fmaf(d0, yv0, acc);
        }
        v[(size_t)a * FDIM + c] += acc;
    }
}

extern "C" void kernel_launch(void* const* d_in, const int* in_sizes, int n_in,
                              void* d_out, int out_size, void* d_ws, size_t ws_size,
                              hipStream_t stream)
{
    const int*   pidx = (const int*)d_in[0];    // [2, P]
    const float* f_ij = (const float*)d_in[1];  // [P, 1, R]
    const float* emb  = (const float*)d_in[3];  // [N, F]
    const float* G    = (const float*)d_in[4];  // [F, R]
    const float* Wi   = (const float*)d_in[5];
    const float* bi   = (const float*)d_in[6];
    const float* Wj   = (const float*)d_in[7];
    const float* bj   = (const float*)d_in[8];
    const float* rW1  = (const float*)d_in[9];
    const float* rb1  = (const float*)d_in[10];
    const float* rW2  = (const float*)d_in[11];
    const float* rb2  = (const float*)d_in[12];
    const float* Wv   = (const float*)d_in[13];
    const float* bv   = (const float*)d_in[14];

    const int P = in_sizes[0] / 2;
    const int N = in_sizes[3] / FDIM;

    float* v = (float*)d_out;

    // workspace layout
    char* ws = (char*)d_ws;
    size_t off = 0;
    float* y      = (float*)(ws + off); off += (size_t)N * FDIM * 4;
    int*   cnt    = (int*)(ws + off);   off += (size_t)N * 4;
    int*   start  = (int*)(ws + off);   off += (size_t)(N + 1) * 4;
    int*   cursor = (int*)(ws + off);   off += (size_t)N * 4;
    off = (off + 15) & ~(size_t)15;
    int*   part   = (int*)(ws + off);   off += (size_t)4096 * 4;
    off = (off + 15) & ~(size_t)15;
    int2*  sorted = (int2*)(ws + off);  off += (size_t)P * 8;
    off = (off + 15) & ~(size_t)15;
    float* wt     = (float*)(ws + off); off += (size_t)9 * 4096 * 4;
    // wt: [0]=Wi^T [1]=Wj^T [2..7]=W1_0^T,W2_0^T,W1_1^T,W2_1^T,W1_2^T,W2_2^T [8]=Wv^T

    const int nPart = (N + 1023) / 1024;
    const int nTiles = (N + 63) >> 6;
    const int gTiles = (nTiles + 3) / 4;   // 1 tile per wave

    dim3 blk(256);
    hipMemsetAsync(cnt, 0, (size_t)N * 4, stream);
    k_tr<<<9, blk, 0, stream>>>(Wi, Wj, rW1, rW2, rW1 + 4096, rW2 + 4096,
                                rW1 + 8192, rW2 + 8192, Wv, wt);
    k_hist<<<1024, blk, 0, stream>>>(pidx, cnt, P);
    k_atoms<<<gTiles, blk, 0, stream>>>(emb, wt, bi, wt + 4096, bj, v, y, N);
    k_scan_a<<<nPart, blk, 0, stream>>>(cnt, part, N);
    k_scan_b<<<1, blk, 0, stream>>>(part, nPart);
    k_scan_c<<<nPart, blk, 0, stream>>>(cnt, part, start, cursor, N, P);
    k_scatter<<<2048, blk, 0, stream>>>(pidx, cursor, sorted, P);
    k_seg<<<4096, blk, 0, stream>>>(sorted, start, f_ij, G, y, v, N);
    k_post<<<gTiles, blk, 0, stream>>>(wt + 2 * 4096, rb1, rb2, wt + 8 * 4096, bv, v, N);
}

// Round 5
// 788.060 us; speedup vs baseline: 1.6703x; 1.4384x over previous
//
#include <hip/hip_runtime.h>
#include <math.h>

#define FDIM 64
#define RDIM 16
#define LN2F 0.69314718055994530942f
#define LTS 68   // LDS tile row stride (floats): 16B-aligned; C-layout b32 access is 2-way (free)

typedef __bf16 bf8_t __attribute__((ext_vector_type(8)));
typedef float  f4_t  __attribute__((ext_vector_type(4)));

// Numerically stable softplus (fast intrinsics)
__device__ __forceinline__ float sp(float x) {
    return fmaxf(x, 0.0f) + __logf(1.0f + __expf(-fabsf(x)));
}

// ---------------- weight prep: fp32 [k][c] -> bf16 B-fragment layout ----------
// For mfma_f32_16x16x32_bf16: b_frag[j] = B[kt*32 + quad*8 + j][nt*16 + (lane&15)]
// Frag array per matrix: frags[kt*4+nt][lane][j] (8 KB each). 9 matrices.
__global__ __launch_bounds__(256) void k_prep(
    const float* s0, const float* s1, const float* s2, const float* s3,
    const float* s4, const float* s5, const float* s6, const float* s7,
    const float* s8, __bf16* __restrict__ dst)
{
    const float* srcs[9] = {s0, s1, s2, s3, s4, s5, s6, s7, s8};
    const float* W = srcs[blockIdx.x];
    __bf16* d = dst + (size_t)blockIdx.x * 4096;
    for (int slot = threadIdx.x; slot < 512; slot += 256) {
        int f = slot >> 6, l = slot & 63;
        int kt = f >> 2, nt = f & 3;
        int row0 = kt * 32 + (l >> 4) * 8;
        int col = nt * 16 + (l & 15);
#pragma unroll
        for (int j = 0; j < 8; ++j)
            d[slot * 8 + j] = (__bf16)W[(row0 + j) * FDIM + col];
    }
}

// ---------------- histogram ----------------
__global__ __launch_bounds__(256) void k_hist(
    const int* __restrict__ idx_i, int* __restrict__ cnt, int P)
{
    int t = blockIdx.x * blockDim.x + threadIdx.x;
    int n = gridDim.x * blockDim.x;
    for (int p = t; p < P; p += n) atomicAdd(&cnt[idx_i[p]], 1);
}

// ---------------- tile in: coalesced global -> wave-private LDS ----------------
__device__ __forceinline__ void tile_in(float* T, const float* __restrict__ src,
                                        int a0, int rows, int lane)
{
#pragma unroll 4
    for (int i = 0; i < 16; ++i) {
        int r = i * 4 + (lane >> 4);
        int col = (lane & 15) * 4;
        float4 val = make_float4(0.f, 0.f, 0.f, 0.f);
        if (r < rows) val = *(const float4*)&src[(size_t)(a0 + r) * FDIM + col];
        *(float4*)&T[r * LTS + col] = val;
    }
}

// build A-fragments (bf16) for a 64x64 LDS tile: aF[mt][kt]
// A[m = lane&15][k = quad*8+j]; act=true applies sp()-LN2F before convert.
__device__ __forceinline__ void build_a(const float* T, int lane, bool actLn2,
                                        bf8_t (&aF)[4][2])
{
    const int l15 = lane & 15, quad = lane >> 4;
#pragma unroll
    for (int mt = 0; mt < 4; ++mt) {
#pragma unroll
        for (int kt = 0; kt < 2; ++kt) {
            const float* rp = &T[(mt * 16 + l15) * LTS + kt * 32 + quad * 8];
            float4 u0 = *(const float4*)rp;
            float4 u1 = *(const float4*)(rp + 4);
            float e[8] = {u0.x, u0.y, u0.z, u0.w, u1.x, u1.y, u1.z, u1.w};
            bf8_t f;
#pragma unroll
            for (int j = 0; j < 8; ++j) {
                float t = actLn2 ? (sp(e[j]) - LN2F) : e[j];
                f[j] = (__bf16)t;
            }
            aF[mt][kt] = f;
        }
    }
}

// ---------------- k_atoms: x=sp(emb)-ln2; v=sp(x@Wi+bi); y=sp(x@Wj+bj) --------
__global__ __launch_bounds__(256) void k_atoms(
    const float* __restrict__ emb, const __bf16* __restrict__ wf,
    const float* __restrict__ bi, const float* __restrict__ bj,
    float* __restrict__ v, float* __restrict__ y, int N)
{
    __shared__ float tile[4][64 * LTS];
    const int lane = threadIdx.x & 63;
    const int wv = threadIdx.x >> 6;
    float* T = tile[wv];
    const int l15 = lane & 15, quad = lane >> 4;

    const bf8_t* wiF = (const bf8_t*)wf;            // matrix 0
    const bf8_t* wjF = (const bf8_t*)(wf + 4096);   // matrix 1
    bf8_t wi[2][4], wj[2][4];
#pragma unroll
    for (int kt = 0; kt < 2; ++kt)
#pragma unroll
        for (int nt = 0; nt < 4; ++nt) {
            wi[kt][nt] = wiF[(kt * 4 + nt) * 64 + lane];
            wj[kt][nt] = wjF[(kt * 4 + nt) * 64 + lane];
        }
    float biv[4], bjv[4];
#pragma unroll
    for (int nt = 0; nt < 4; ++nt) {
        biv[nt] = bi[nt * 16 + l15];
        bjv[nt] = bj[nt * 16 + l15];
    }

    const int nTiles = (N + 63) >> 6;
    for (int t = blockIdx.x * 4 + wv; t < nTiles; t += gridDim.x * 4) {
        const int a0 = t << 6;
        const int rows = min(64, N - a0);
        tile_in(T, emb, a0, rows, lane);
        bf8_t aF[4][2];
        build_a(T, lane, true, aF);
#pragma unroll
        for (int mt = 0; mt < 4; ++mt)
#pragma unroll
            for (int nt = 0; nt < 4; ++nt) {
                f4_t acc = {biv[nt], biv[nt], biv[nt], biv[nt]};
                acc = __builtin_amdgcn_mfma_f32_16x16x32_bf16(aF[mt][0], wi[0][nt], acc, 0, 0, 0);
                acc = __builtin_amdgcn_mfma_f32_16x16x32_bf16(aF[mt][1], wi[1][nt], acc, 0, 0, 0);
#pragma unroll
                for (int reg = 0; reg < 4; ++reg) {
                    int r = mt * 16 + quad * 4 + reg;
                    if (r < rows) v[(size_t)(a0 + r) * FDIM + nt * 16 + l15] = sp(acc[reg]);
                }
            }
#pragma unroll
        for (int mt = 0; mt < 4; ++mt)
#pragma unroll
            for (int nt = 0; nt < 4; ++nt) {
                f4_t acc = {bjv[nt], bjv[nt], bjv[nt], bjv[nt]};
                acc = __builtin_amdgcn_mfma_f32_16x16x32_bf16(aF[mt][0], wj[0][nt], acc, 0, 0, 0);
                acc = __builtin_amdgcn_mfma_f32_16x16x32_bf16(aF[mt][1], wj[1][nt], acc, 0, 0, 0);
#pragma unroll
                for (int reg = 0; reg < 4; ++reg) {
                    int r = mt * 16 + quad * 4 + reg;
                    if (r < rows) y[(size_t)(a0 + r) * FDIM + nt * 16 + l15] = sp(acc[reg]);
                }
            }
    }
}

// ---------------- k_post: fused 3 residual blocks + final projection (MFMA) ---
__global__ __launch_bounds__(256) void k_post(
    const __bf16* __restrict__ wf,   // matrices 2..8: W1_0,W2_0,W1_1,W2_1,W1_2,W2_2,Wv
    const float* __restrict__ rb1, const float* __restrict__ rb2,
    const float* __restrict__ bv,
    float* __restrict__ v, int N)
{
    __shared__ float tile[4][64 * LTS];
    const int lane = threadIdx.x & 63;
    const int wv = threadIdx.x >> 6;
    float* T = tile[wv];
    const int l15 = lane & 15, quad = lane >> 4;

    float b1v[3][4], b2v[3][4], bvv[4];
#pragma unroll
    for (int l = 0; l < 3; ++l)
#pragma unroll
        for (int nt = 0; nt < 4; ++nt) {
            b1v[l][nt] = rb1[l * FDIM + nt * 16 + l15];
            b2v[l][nt] = rb2[l * FDIM + nt * 16 + l15];
        }
#pragma unroll
    for (int nt = 0; nt < 4; ++nt) bvv[nt] = bv[nt * 16 + l15];

    const int nTiles = (N + 63) >> 6;
    for (int t = blockIdx.x * 4 + wv; t < nTiles; t += gridDim.x * 4) {
        const int a0 = t << 6;
        const int rows = min(64, N - a0);
        tile_in(T, v, a0, rows, lane);
        // v in C layout (fp32 resident)
        float vC[16][4];
#pragma unroll
        for (int mt = 0; mt < 4; ++mt)
#pragma unroll
            for (int nt = 0; nt < 4; ++nt)
#pragma unroll
                for (int reg = 0; reg < 4; ++reg)
                    vC[mt * 4 + nt][reg] =
                        T[(mt * 16 + quad * 4 + reg) * LTS + nt * 16 + l15];

        for (int l = 0; l < 3; ++l) {
            const bf8_t* w1f = (const bf8_t*)(wf + (size_t)(2 * l) * 4096);
            const bf8_t* w2f = (const bf8_t*)(wf + (size_t)(2 * l + 1) * 4096);
            // h = sp(v @ W1 + b1)  (A-frags of v from T)
            bf8_t aF[4][2];
            build_a(T, lane, false, aF);
#pragma unroll
            for (int mt = 0; mt < 4; ++mt)
#pragma unroll
                for (int nt = 0; nt < 4; ++nt) {
                    f4_t acc = {b1v[l][nt], b1v[l][nt], b1v[l][nt], b1v[l][nt]};
                    acc = __builtin_amdgcn_mfma_f32_16x16x32_bf16(aF[mt][0], w1f[(0 * 4 + nt) * 64 + lane], acc, 0, 0, 0);
                    acc = __builtin_amdgcn_mfma_f32_16x16x32_bf16(aF[mt][1], w1f[(1 * 4 + nt) * 64 + lane], acc, 0, 0, 0);
#pragma unroll
                    for (int reg = 0; reg < 4; ++reg)
                        T[(mt * 16 + quad * 4 + reg) * LTS + nt * 16 + l15] = sp(acc[reg]);
                }
            // d = h @ W2 + b2 ; v += d
            bf8_t hF[4][2];
            build_a(T, lane, false, hF);
#pragma unroll
            for (int mt = 0; mt < 4; ++mt)
#pragma unroll
                for (int nt = 0; nt < 4; ++nt) {
                    f4_t acc = {b2v[l][nt], b2v[l][nt], b2v[l][nt], b2v[l][nt]};
                    acc = __builtin_amdgcn_mfma_f32_16x16x32_bf16(hF[mt][0], w2f[(0 * 4 + nt) * 64 + lane], acc, 0, 0, 0);
                    acc = __builtin_amdgcn_mfma_f32_16x16x32_bf16(hF[mt][1], w2f[(1 * 4 + nt) * 64 + lane], acc, 0, 0, 0);
#pragma unroll
                    for (int reg = 0; reg < 4; ++reg)
                        vC[mt * 4 + nt][reg] += acc[reg];
                }
            // publish updated v to T for the next layer's A-read
            if (l < 2) {
#pragma unroll
                for (int mt = 0; mt < 4; ++mt)
#pragma unroll
                    for (int nt = 0; nt < 4; ++nt)
#pragma unroll
                        for (int reg = 0; reg < 4; ++reg)
                            T[(mt * 16 + quad * 4 + reg) * LTS + nt * 16 + l15] =
                                vC[mt * 4 + nt][reg];
            }
        }
        // out = sp(v) @ Wv + bv
#pragma unroll
        for (int mt = 0; mt < 4; ++mt)
#pragma unroll
            for (int nt = 0; nt < 4; ++nt)
#pragma unroll
                for (int reg = 0; reg < 4; ++reg)
                    T[(mt * 16 + quad * 4 + reg) * LTS + nt * 16 + l15] =
                        sp(vC[mt * 4 + nt][reg]);
        bf8_t fF[4][2];
        build_a(T, lane, false, fF);
        const bf8_t* wvf = (const bf8_t*)(wf + (size_t)6 * 4096);
#pragma unroll
        for (int mt = 0; mt < 4; ++mt)
#pragma unroll
            for (int nt = 0; nt < 4; ++nt) {
                f4_t acc = {bvv[nt], bvv[nt], bvv[nt], bvv[nt]};
                acc = __builtin_amdgcn_mfma_f32_16x16x32_bf16(fF[mt][0], wvf[(0 * 4 + nt) * 64 + lane], acc, 0, 0, 0);
                acc = __builtin_amdgcn_mfma_f32_16x16x32_bf16(fF[mt][1], wvf[(1 * 4 + nt) * 64 + lane], acc, 0, 0, 0);
#pragma unroll
                for (int reg = 0; reg < 4; ++reg) {
                    int r = mt * 16 + quad * 4 + reg;
                    if (r < rows) v[(size_t)(a0 + r) * FDIM + nt * 16 + l15] = acc[reg];
                }
            }
    }
}

// ---------------- scan / scatter ----------------
__global__ __launch_bounds__(256) void k_scan_a(
    const int* __restrict__ cnt, int* __restrict__ part, int N)
{
    __shared__ int red[256];
    int b = blockIdx.x, t = threadIdx.x;
    int base = b * 1024 + t * 4;
    int s = 0;
#pragma unroll
    for (int i = 0; i < 4; ++i) { int a = base + i; if (a < N) s += cnt[a]; }
    red[t] = s; __syncthreads();
    for (int off = 128; off > 0; off >>= 1) {
        if (t < off) red[t] += red[t + off];
        __syncthreads();
    }
    if (t == 0) part[b] = red[0];
}

__global__ __launch_bounds__(256) void k_scan_b(int* __restrict__ part, int nPart)
{
    __shared__ int lds[256];
    int t = threadIdx.x;
    int base = t * 4;
    int v[4]; int s = 0;
#pragma unroll
    for (int i = 0; i < 4; ++i) { v[i] = (base + i < nPart) ? part[base + i] : 0; s += v[i]; }
    lds[t] = s; __syncthreads();
    int run = s;
    for (int off = 1; off < 256; off <<= 1) {
        int x = (t >= off) ? lds[t - off] : 0;
        __syncthreads();
        lds[t] += x;
        __syncthreads();
    }
    int excl = lds[t] - run;
#pragma unroll
    for (int i = 0; i < 4; ++i) { if (base + i < nPart) { part[base + i] = excl; excl += v[i]; } }
}

__global__ __launch_bounds__(256) void k_scan_c(
    const int* __restrict__ cnt, const int* __restrict__ part,
    int* __restrict__ start, int* __restrict__ cursor, int N, int P)
{
    __shared__ int lds[256];
    int b = blockIdx.x, t = threadIdx.x;
    int base = b * 1024 + t * 4;
    int v[4]; int s = 0;
#pragma unroll
    for (int i = 0; i < 4; ++i) { int a = base + i; v[i] = (a < N) ? cnt[a] : 0; s += v[i]; }
    lds[t] = s; __syncthreads();
    int run = s;
    for (int off = 1; off < 256; off <<= 1) {
        int x = (t >= off) ? lds[t - off] : 0;
        __syncthreads();
        lds[t] += x;
        __syncthreads();
    }
    int pre = part[b] + (lds[t] - run);
#pragma unroll
    for (int i = 0; i < 4; ++i) {
        int a = base + i;
        if (a < N) { start[a] = pre; cursor[a] = pre; pre += v[i]; }
    }
    if (b == 0 && t == 0) start[N] = P;
}

__global__ __launch_bounds__(256) void k_scatter(
    const int* __restrict__ pidx, int* __restrict__ cursor,
    int2* __restrict__ sorted, int P)
{
    int t = blockIdx.x * blockDim.x + threadIdx.x;
    int n = gridDim.x * blockDim.x;
    for (int p = t; p < P; p += n) {
        int i = pidx[p], j = pidx[P + p];
        int pos = atomicAdd(&cursor[i], 1);
        sorted[pos] = make_int2(p, j);
    }
}

// ---------------- k_seg: scalarized f via readfirstlane, VMEM only for y ------
__device__ __forceinline__ float fdot_s(const float* __restrict__ f,
                                        float4 g0, float4 g1, float4 g2, float4 g3)
{
    float d = f[0] * g0.x;
    d = fmaf(f[1], g0.y, d);  d = fmaf(f[2], g0.z, d);  d = fmaf(f[3], g0.w, d);
    d = fmaf(f[4], g1.x, d);  d = fmaf(f[5], g1.y, d);  d = fmaf(f[6], g1.z, d);  d = fmaf(f[7], g1.w, d);
    d = fmaf(f[8], g2.x, d);  d = fmaf(f[9], g2.y, d);  d = fmaf(f[10], g2.z, d); d = fmaf(f[11], g2.w, d);
    d = fmaf(f[12], g3.x, d); d = fmaf(f[13], g3.y, d); d = fmaf(f[14], g3.z, d); d = fmaf(f[15], g3.w, d);
    return d;
}

__global__ __launch_bounds__(256) void k_seg(
    const int2* __restrict__ sorted, const int* __restrict__ start,
    const float* __restrict__ f_ij, const float* __restrict__ G,
    const float* __restrict__ y, float* __restrict__ v, int N)
{
    const int c = threadIdx.x & 63;
    const int w = __builtin_amdgcn_readfirstlane((blockIdx.x << 2) | (threadIdx.x >> 6));
    const int nw = gridDim.x << 2;
    float4 g0, g1, g2, g3;
    {
        const float4* gp = (const float4*)(G + c * RDIM);
        g0 = gp[0]; g1 = gp[1]; g2 = gp[2]; g3 = gp[3];
    }
    for (int a = w; a < N; a += nw) {
        const int s = start[a], e = start[a + 1];
        float acc = 0.0f;
        int q = s;
        for (; q + 2 <= e; q += 2) {
            int2 E0 = sorted[q], E1 = sorted[q + 1];
            int p0 = __builtin_amdgcn_readfirstlane(E0.x);
            int j0 = __builtin_amdgcn_readfirstlane(E0.y);
            int p1 = __builtin_amdgcn_readfirstlane(E1.x);
            int j1 = __builtin_amdgcn_readfirstlane(E1.y);
            float y0 = y[(size_t)j0 * FDIM + c];
            float y1 = y[(size_t)j1 * FDIM + c];
            float d0 = fdot_s(f_ij + (size_t)p0 * RDIM, g0, g1, g2, g3);
            float d1 = fdot_s(f_ij + (size_t)p1 * RDIM, g0, g1, g2, g3);
            acc = fmaf(d0, y0, acc);
            acc = fmaf(d1, y1, acc);
        }
        if (q < e) {
            int2 E0 = sorted[q];
            int p0 = __builtin_amdgcn_readfirstlane(E0.x);
            int j0 = __builtin_amdgcn_readfirstlane(E0.y);
            float y0 = y[(size_t)j0 * FDIM + c];
            acc = fmaf(fdot_s(f_ij + (size_t)p0 * RDIM, g0, g1, g2, g3), y0, acc);
        }
        v[(size_t)a * FDIM + c] += acc;
    }
}

extern "C" void kernel_launch(void* const* d_in, const int* in_sizes, int n_in,
                              void* d_out, int out_size, void* d_ws, size_t ws_size,
                              hipStream_t stream)
{
    const int*   pidx = (const int*)d_in[0];    // [2, P]
    const float* f_ij = (const float*)d_in[1];  // [P, 1, R]
    const float* emb  = (const float*)d_in[3];  // [N, F]
    const float* G    = (const float*)d_in[4];  // [F, R]
    const float* Wi   = (const float*)d_in[5];
    const float* bi   = (const float*)d_in[6];
    const float* Wj   = (const float*)d_in[7];
    const float* bj   = (const float*)d_in[8];
    const float* rW1  = (const float*)d_in[9];
    const float* rb1  = (const float*)d_in[10];
    const float* rW2  = (const float*)d_in[11];
    const float* rb2  = (const float*)d_in[12];
    const float* Wv   = (const float*)d_in[13];
    const float* bv   = (const float*)d_in[14];

    const int P = in_sizes[0] / 2;
    const int N = in_sizes[3] / FDIM;

    float* v = (float*)d_out;

    // workspace layout
    char* ws = (char*)d_ws;
    size_t off = 0;
    float*  y      = (float*)(ws + off);  off += (size_t)N * FDIM * 4;
    int*    cnt    = (int*)(ws + off);    off += (size_t)N * 4;
    int*    start  = (int*)(ws + off);    off += (size_t)(N + 1) * 4;
    int*    cursor = (int*)(ws + off);    off += (size_t)N * 4;
    off = (off + 15) & ~(size_t)15;
    int*    part   = (int*)(ws + off);    off += (size_t)4096 * 4;
    off = (off + 15) & ~(size_t)15;
    int2*   sorted = (int2*)(ws + off);   off += (size_t)P * 8;
    off = (off + 15) & ~(size_t)15;
    __bf16* wf     = (__bf16*)(ws + off); off += (size_t)9 * 4096 * 2;
    // wf matrices: 0=Wi 1=Wj 2=W1_0 3=W2_0 4=W1_1 5=W2_1 6=W1_2 7=W2_2 8=Wv

    const int nPart = (N + 1023) / 1024;
    const int nTiles = (N + 63) >> 6;
    const int gTiles = (nTiles + 3) / 4;   // 1 tile per wave

    dim3 blk(256);
    hipMemsetAsync(cnt, 0, (size_t)N * 4, stream);
    k_prep<<<9, blk, 0, stream>>>(Wi, Wj, rW1, rW2, rW1 + 4096, rW2 + 4096,
                                  rW1 + 8192, rW2 + 8192, Wv, wf);
    k_hist<<<1024, blk, 0, stream>>>(pidx, cnt, P);
    k_atoms<<<gTiles, blk, 0, stream>>>(emb, wf, bi, bj, v, y, N);
    k_scan_a<<<nPart, blk, 0, stream>>>(cnt, part, N);
    k_scan_b<<<1, blk, 0, stream>>>(part, nPart);
    k_scan_c<<<nPart, blk, 0, stream>>>(cnt, part, start, cursor, N, P);
    k_scatter<<<2048, blk, 0, stream>>>(pidx, cursor, sorted, P);
    k_seg<<<4096, blk, 0, stream>>>(sorted, start, f_ij, G, y, v, N);
    k_post<<<gTiles, blk, 0, stream>>>(wf + (size_t)2 * 4096, rb1, rb2, bv, v, N);
}